// Round 6
// baseline (362.765 us; speedup 1.0000x reference)
//
#include <hip/hip_runtime.h>

#define NI 32
#define CI 128
#define HI 112
#define WI 112
#define OC 256
#define HO 110
#define WO 110

typedef float f32x4 __attribute__((ext_vector_type(4)));
typedef short s16x8 __attribute__((ext_vector_type(8)));

typedef const unsigned int __attribute__((address_space(1))) gu32;
typedef unsigned int __attribute__((address_space(3))) lu32;

__device__ __forceinline__ ushort f2bf(float f) {
  union { float f; unsigned int u; } x; x.f = f;
  unsigned int r = x.u + 0x7FFFu + ((x.u >> 16) & 1u);
  return (ushort)(r >> 16);
}

// weight [oc][c][kh][kw] fp32 -> wp [kk][cq][oc][32ch] bf16  (cq = 32-ch quarter)
__global__ __launch_bounds__(256) void pack_w_kernel(const float* __restrict__ w,
                                                     ushort* __restrict__ wp) {
  int i = blockIdx.x * 256 + threadIdx.x;  // 294912
  int e = i & 7;
  int k8 = (i >> 3) & 3;
  int oc = (i >> 5) & 255;
  int cq = (i >> 13) & 3;
  int kk = i >> 15;  // 0..8
  int ch = cq * 32 + k8 * 8 + e;
  int kh = kk / 3, kw = kk - kh * 3;
  wp[i] = f2bf(w[((oc * CI + ch) * 3 + kh) * 3 + kw]);
}

// x [n][c][h][w] fp32 -> xn [n][cq][h][w][32c] bf16.
// Coalesced reads (lane<->w), 16B-chunk XOR-swizzled LDS transpose, uint4 writes.
__global__ __launch_bounds__(256) void to_nhwc_kernel(const float* __restrict__ x,
                                                      ushort* __restrict__ xn) {
  __shared__ ushort lds[1792 * 8];  // 1792 16B chunks (112 w x 16 chunks), 28 KB
  int b = blockIdx.x;               // n*112 + h
  int n = b / HI;
  int h = b - n * HI;
  const float* xr = x + ((size_t)n * CI * HI) * WI + (size_t)h * WI;
  int t = threadIdx.x;
  int w = t & 127;   // active if < 112
  int cph = t >> 7;  // 0..1
  if (w < WI) {
    #pragma unroll
    for (int it = 0; it < 32; ++it) {
      int cp = it * 2 + cph;  // channel pair 0..63
      int c = cp * 2;
      float f0 = xr[(size_t)c * (HI * WI) + w];
      float f1 = xr[(size_t)(c + 1) * (HI * WI) + w];
      unsigned int pk = (unsigned int)f2bf(f0) | ((unsigned int)f2bf(f1) << 16);
      int chunk = w * 16 + ((cp >> 2) ^ (w & 15));
      *(unsigned int*)((char*)lds + chunk * 16 + (cp & 3) * 4) = pk;
    }
  }
  __syncthreads();
  #pragma unroll
  for (int it = 0; it < 7; ++it) {
    int j = it * 256 + t;  // chunk id: w = j>>4, c8 = j&15
    int w2 = j >> 4, c8 = j & 15;
    int src = w2 * 16 + (c8 ^ (w2 & 15));
    uint4 v = *(const uint4*)((const char*)lds + src * 16);
    int cq = c8 >> 2, g = c8 & 3;
    *(uint4*)&xn[((((size_t)n * 4 + cq) * HI + h) * WI + w2) * 32 + g * 8] = v;
  }
}

// Implicit GEMM, 16x16x32 MFMA. Block = 256 thr (4 waves = 4 oc quarters),
// one output row x 256 oc. K = 4 quarters of 32 ch, double-buffered LDS staged
// during compute. A-prefetch: ring depth 4, distance 3 — A-sets for the first
// 3 steps of each quarter are issued BEFORE that quarter's stage, so A-waits
// never retire behind the bulk stage loads (vmcnt is in-order).
__global__ __launch_bounds__(256, 2) void conv_mfma_kernel(const ushort* __restrict__ xn,
                                                           const ushort* __restrict__ wp,
                                                           const float* __restrict__ bias,
                                                           float* __restrict__ out) {
  __shared__ ushort lds[2 * 340 * 32];  // 2 quarter buffers, 21.75 KB each
  const int bid = blockIdx.x;
  // bijective XCD swizzle (3520 = 8*440): consecutive oh share an XCD's L2
  const int orig = (bid & 7) * 440 + (bid >> 3);
  const int n = orig / HO;
  const int oh = orig - n * HO;
  const int t = threadIdx.x;
  const int lane = t & 63;
  const int wid = t >> 6;  // oc quarter
  const int lane15 = lane & 15;
  const int laneh = lane >> 4;  // 0..3
  const int oc0 = wid * 64;
  char* ldsb = (char*)lds;

  f32x4 acc[4][7] = {};  // [mf: oc 16-frag][nf: ow 16-frag]
  s16x8 abuf[4][4];      // A ring (depth 4, prefetch distance 3; static idx g&3)

#define A_PREFETCH(gg)                                                                   \
  {                                                                                      \
    const int q_ = (gg) / 9, kk_ = (gg) - q_ * 9;                                        \
    const ushort* wb_ = wp + ((size_t)(kk_ * 4 + q_)) * 8192 + (oc0 + lane15) * 32 +     \
                        laneh * 8;                                                       \
    _Pragma("unroll") for (int mf = 0; mf < 4; ++mf)                                     \
        abuf[(gg) & 3][mf] = *(const s16x8*)(wb_ + mf * 512);                            \
  }

#define STAGE(qq)                                                                        \
  {                                                                                      \
    const char* gsb_ =                                                                   \
        (const char*)(xn + ((((size_t)n * 4 + (qq)) * HI + oh) * WI) * 32);              \
    char* ldst_ = ldsb + (((qq) & 1) * 21760);                                           \
    _Pragma("unroll") for (int i = 0; i < 6; ++i) {                                      \
      int idx = i * 256 + t;                                                             \
      if (idx < 1344) {                                                                  \
        int L = idx * 16;                                                                \
        int go = L ^ (((L >> 7) & 3) << 4);                                              \
        __builtin_amdgcn_global_load_lds((gu32*)(gsb_ + go), (lu32*)(ldst_ + L), 16, 0,  \
                                         0);                                             \
      }                                                                                  \
    }                                                                                    \
  }

  // ---- prologue: A-sets for g=0,1,2, then stage(0) ----
  A_PREFETCH(0)
  A_PREFETCH(1)
  A_PREFETCH(2)
  STAGE(0)
  __syncthreads();  // drains prologue stage + preloads (once per block)

  #pragma unroll
  for (int q = 0; q < 4; ++q) {
    if (q) __syncthreads();  // prev-quarter readers done; stage(q) landed
    if (q < 3) STAGE(q + 1)  // issued AFTER this quarter's first-3 A-sets
    const int qb = (q & 1) * 21760;
    #pragma unroll
    for (int kk = 0; kk < 9; ++kk) {
      const int g = q * 9 + kk;
      const int kh = kk / 3, kw = kk - kh * 3;
      if (g + 3 < 36) A_PREFETCH(g + 3)  // consumed 3 steps later: stage retired by then
      // B fragments from swizzled LDS quarter
      s16x8 b[7];
      #pragma unroll
      for (int nf = 0; nf < 7; ++nf) {
        int R = kh * WI + nf * 16 + lane15 + kw;  // staged pixel-row index
        int addr = qb + (R << 6) + ((laneh ^ ((R >> 1) & 3)) << 4);
        b[nf] = *(const s16x8*)(ldsb + addr);
      }
      __builtin_amdgcn_s_setprio(1);
      #pragma unroll
      for (int mf = 0; mf < 4; ++mf)
        #pragma unroll
        for (int nf = 0; nf < 7; ++nf)
          acc[mf][nf] = __builtin_amdgcn_mfma_f32_16x16x32_bf16(abuf[g & 3][mf], b[nf],
                                                                acc[mf][nf], 0, 0, 0);
      __builtin_amdgcn_s_setprio(0);
    }
  }
#undef A_PREFETCH
#undef STAGE

  // ---- epilogue: D col=lane15 -> ow, row=laneh*4+r -> oc ----
  float* outb = out + ((size_t)n * OC) * (HO * WO) + (size_t)oh * WO;
  #pragma unroll
  for (int mf = 0; mf < 4; ++mf) {
    #pragma unroll
    for (int r = 0; r < 4; ++r) {
      const int oc = oc0 + mf * 16 + laneh * 4 + r;
      const float bv = bias[oc];
      float* op = outb + (size_t)oc * (HO * WO);
      #pragma unroll
      for (int nf = 0; nf < 7; ++nf) {
        int ow = nf * 16 + lane15;
        if (ow < WO) op[ow] = acc[mf][nf][r] + bv;
      }
    }
  }
}

// Correctness fallback if ws is too small for the packed bf16 buffers.
__global__ __launch_bounds__(256) void conv_naive_kernel(const float* __restrict__ x,
                                                         const float* __restrict__ w,
                                                         const float* __restrict__ bias,
                                                         float* __restrict__ out) {
  long i = (long)blockIdx.x * 256 + threadIdx.x;
  const long total = (long)NI * OC * HO * WO;
  if (i >= total) return;
  int ow = (int)(i % WO);
  long r1 = i / WO;
  int oh = (int)(r1 % HO);
  long r2 = r1 / HO;
  int oc = (int)(r2 % OC);
  int n = (int)(r2 / OC);
  float s = bias[oc];
  const float* xb = x + ((size_t)n * CI * HI) * WI;
  const float* wb = w + (size_t)oc * CI * 9;
  for (int c = 0; c < CI; ++c)
    for (int kh = 0; kh < 3; ++kh)
      for (int kw = 0; kw < 3; ++kw)
        s += xb[((size_t)c * HI + oh + kh) * WI + ow + kw] * wb[(c * 3 + kh) * 3 + kw];
  out[i] = s;
}

extern "C" void kernel_launch(void* const* d_in, const int* in_sizes, int n_in,
                              void* d_out, int out_size, void* d_ws, size_t ws_size,
                              hipStream_t stream) {
  const float* x = (const float*)d_in[0];
  const float* w = (const float*)d_in[1];
  const float* bias = (const float*)d_in[2];
  float* out = (float*)d_out;

  const size_t xn_elems = (size_t)NI * 4 * HI * WI * 32;  // 51,380,224
  const size_t wp_elems = (size_t)9 * 4 * 256 * 32;       // 294,912
  const size_t need = (xn_elems + wp_elems) * sizeof(ushort);

  if (ws_size >= need) {
    ushort* xnw = (ushort*)d_ws;
    ushort* wpw = xnw + xn_elems;
    hipLaunchKernelGGL(pack_w_kernel, dim3((unsigned)(wp_elems / 256)), dim3(256), 0, stream,
                       w, wpw);
    hipLaunchKernelGGL(to_nhwc_kernel, dim3(NI * HI), dim3(256), 0, stream, x, xnw);
    hipLaunchKernelGGL(conv_mfma_kernel, dim3(NI * HO), dim3(256), 0, stream, xnw, wpw, bias,
                       out);
  } else {
    long total = (long)NI * OC * HO * WO;
    hipLaunchKernelGGL(conv_naive_kernel, dim3((unsigned)((total + 255) / 256)), dim3(256), 0,
                       stream, x, w, bias, out);
  }
}

// Round 7
// 323.451 us; speedup vs baseline: 1.1215x; 1.1215x over previous
//
#include <hip/hip_runtime.h>

#define NI 32
#define CI 128
#define HI 112
#define WI 112
#define OC 256
#define HO 110
#define WO 110

typedef float f32x4 __attribute__((ext_vector_type(4)));
typedef short s16x8 __attribute__((ext_vector_type(8)));

typedef const unsigned int __attribute__((address_space(1))) gu32;
typedef unsigned int __attribute__((address_space(3))) lu32;

__device__ __forceinline__ ushort f2bf(float f) {
  union { float f; unsigned int u; } x; x.f = f;
  unsigned int r = x.u + 0x7FFFu + ((x.u >> 16) & 1u);
  return (ushort)(r >> 16);
}

// weight [oc][c][kh][kw] fp32 -> wp [kk][cq][oc][32ch] bf16  (cq = 32-ch quarter)
__global__ __launch_bounds__(256) void pack_w_kernel(const float* __restrict__ w,
                                                     ushort* __restrict__ wp) {
  int i = blockIdx.x * 256 + threadIdx.x;  // 294912
  int e = i & 7;
  int k8 = (i >> 3) & 3;
  int oc = (i >> 5) & 255;
  int cq = (i >> 13) & 3;
  int kk = i >> 15;  // 0..8
  int ch = cq * 32 + k8 * 8 + e;
  int kh = kk / 3, kw = kk - kh * 3;
  wp[i] = f2bf(w[((oc * CI + ch) * 3 + kh) * 3 + kw]);
}

// x [n][c][h][w] fp32 -> xn [n][cq][h][w][32c] bf16.
// Coalesced reads (lane<->w), 16B-chunk XOR-swizzled LDS transpose, uint4 writes.
__global__ __launch_bounds__(256) void to_nhwc_kernel(const float* __restrict__ x,
                                                      ushort* __restrict__ xn) {
  __shared__ ushort lds[1792 * 8];  // 1792 16B chunks (112 w x 16 chunks), 28 KB
  int b = blockIdx.x;               // n*112 + h
  int n = b / HI;
  int h = b - n * HI;
  const float* xr = x + ((size_t)n * CI * HI) * WI + (size_t)h * WI;
  int t = threadIdx.x;
  int w = t & 127;   // active if < 112
  int cph = t >> 7;  // 0..1
  if (w < WI) {
    #pragma unroll
    for (int it = 0; it < 32; ++it) {
      int cp = it * 2 + cph;  // channel pair 0..63
      int c = cp * 2;
      float f0 = xr[(size_t)c * (HI * WI) + w];
      float f1 = xr[(size_t)(c + 1) * (HI * WI) + w];
      unsigned int pk = (unsigned int)f2bf(f0) | ((unsigned int)f2bf(f1) << 16);
      int chunk = w * 16 + ((cp >> 2) ^ (w & 15));
      *(unsigned int*)((char*)lds + chunk * 16 + (cp & 3) * 4) = pk;
    }
  }
  __syncthreads();
  #pragma unroll
  for (int it = 0; it < 7; ++it) {
    int j = it * 256 + t;  // chunk id: w = j>>4, c8 = j&15
    int w2 = j >> 4, c8 = j & 15;
    int src = w2 * 16 + (c8 ^ (w2 & 15));
    uint4 v = *(const uint4*)((const char*)lds + src * 16);
    int cq = c8 >> 2, g = c8 & 3;
    *(uint4*)&xn[((((size_t)n * 4 + cq) * HI + h) * WI + w2) * 32 + g * 8] = v;
  }
}

// Implicit GEMM, 16x16x32 MFMA. Block = 256 thr (4 waves = 4 oc quarters),
// one output row x 256 oc. K = 4 quarters of 32 ch, double-buffered LDS.
// Stage of quarter q+1 is SPREAD across steps kk=1..6 of quarter q (one
// 256-load chunk per step, issued after that step's A-prefetch), so in-order
// vmcnt never makes an A-wait sit behind more than one ~1-step-old chunk.
__global__ __launch_bounds__(256, 2) void conv_mfma_kernel(const ushort* __restrict__ xn,
                                                           const ushort* __restrict__ wp,
                                                           const float* __restrict__ bias,
                                                           float* __restrict__ out) {
  __shared__ ushort lds[2 * 340 * 32];  // 2 quarter buffers, 21.75 KB each
  const int bid = blockIdx.x;
  // bijective XCD swizzle (3520 = 8*440): consecutive oh share an XCD's L2
  const int orig = (bid & 7) * 440 + (bid >> 3);
  const int n = orig / HO;
  const int oh = orig - n * HO;
  const int t = threadIdx.x;
  const int lane = t & 63;
  const int wid = t >> 6;  // oc quarter
  const int lane15 = lane & 15;
  const int laneh = lane >> 4;  // 0..3
  const int oc0 = wid * 64;
  char* ldsb = (char*)lds;

  f32x4 acc[4][7] = {};  // [mf: oc 16-frag][nf: ow 16-frag]
  s16x8 abuf[2][4];      // A double-buffer (static indices after unroll)

#define A_PREFETCH(gg)                                                                   \
  {                                                                                      \
    const int q_ = (gg) / 9, kk_ = (gg) - q_ * 9;                                        \
    const ushort* wb_ = wp + ((size_t)(kk_ * 4 + q_)) * 8192 + (oc0 + lane15) * 32 +     \
                        laneh * 8;                                                       \
    _Pragma("unroll") for (int mf = 0; mf < 4; ++mf)                                     \
        abuf[(gg) & 1][mf] = *(const s16x8*)(wb_ + mf * 512);                            \
  }

// one 256-load (4 KB) chunk of the 1344-load stage of quarter qq
#define STAGE_CHUNK(qq, ii)                                                              \
  {                                                                                      \
    const char* gsb_ =                                                                   \
        (const char*)(xn + ((((size_t)n * 4 + (qq)) * HI + oh) * WI) * 32);              \
    char* ldst_ = ldsb + (((qq) & 1) * 21760);                                           \
    int idx = (ii) * 256 + t;                                                            \
    if (idx < 1344) {                                                                    \
      int L = idx * 16;                                                                  \
      int go = L ^ (((L >> 7) & 3) << 4);                                                \
      __builtin_amdgcn_global_load_lds((gu32*)(gsb_ + go), (lu32*)(ldst_ + L), 16, 0,    \
                                       0);                                               \
    }                                                                                    \
  }

  // ---- prologue: stage quarter 0 (all 6 chunks), prefetch A(g=0) ----
  {
    #pragma unroll
    for (int i = 0; i < 6; ++i) STAGE_CHUNK(0, i)
    A_PREFETCH(0)
  }
  __syncthreads();  // drains prologue stage + preload

  #pragma unroll
  for (int q = 0; q < 4; ++q) {
    if (q) __syncthreads();  // prev-quarter readers done; stage(q) landed
    const int qb = (q & 1) * 21760;
    #pragma unroll
    for (int kk = 0; kk < 9; ++kk) {
      const int g = q * 9 + kk;
      const int kh = kk / 3, kw = kk - kh * 3;
      // prefetch A for g+1 (one step ahead) — issued BEFORE this step's stage chunk
      if (g + 1 < 36) A_PREFETCH(g + 1)
      // spread stage of quarter q+1: chunk kk-1 at steps kk=1..6
      if (q < 3 && kk >= 1 && kk <= 6) STAGE_CHUNK(q + 1, kk - 1)
      // B fragments from swizzled LDS quarter
      s16x8 b[7];
      #pragma unroll
      for (int nf = 0; nf < 7; ++nf) {
        int R = kh * WI + nf * 16 + lane15 + kw;  // staged pixel-row index
        int addr = qb + (R << 6) + ((laneh ^ ((R >> 1) & 3)) << 4);
        b[nf] = *(const s16x8*)(ldsb + addr);
      }
      __builtin_amdgcn_s_setprio(1);
      #pragma unroll
      for (int mf = 0; mf < 4; ++mf)
        #pragma unroll
        for (int nf = 0; nf < 7; ++nf)
          acc[mf][nf] = __builtin_amdgcn_mfma_f32_16x16x32_bf16(abuf[g & 1][mf], b[nf],
                                                                acc[mf][nf], 0, 0, 0);
      __builtin_amdgcn_s_setprio(0);
    }
  }
#undef A_PREFETCH
#undef STAGE_CHUNK

  // ---- epilogue: D col=lane15 -> ow, row=laneh*4+r -> oc ----
  float* outb = out + ((size_t)n * OC) * (HO * WO) + (size_t)oh * WO;
  #pragma unroll
  for (int mf = 0; mf < 4; ++mf) {
    #pragma unroll
    for (int r = 0; r < 4; ++r) {
      const int oc = oc0 + mf * 16 + laneh * 4 + r;
      const float bv = bias[oc];
      float* op = outb + (size_t)oc * (HO * WO);
      #pragma unroll
      for (int nf = 0; nf < 7; ++nf) {
        int ow = nf * 16 + lane15;
        if (ow < WO) op[ow] = acc[mf][nf][r] + bv;
      }
    }
  }
}

// Correctness fallback if ws is too small for the packed bf16 buffers.
__global__ __launch_bounds__(256) void conv_naive_kernel(const float* __restrict__ x,
                                                         const float* __restrict__ w,
                                                         const float* __restrict__ bias,
                                                         float* __restrict__ out) {
  long i = (long)blockIdx.x * 256 + threadIdx.x;
  const long total = (long)NI * OC * HO * WO;
  if (i >= total) return;
  int ow = (int)(i % WO);
  long r1 = i / WO;
  int oh = (int)(r1 % HO);
  long r2 = r1 / HO;
  int oc = (int)(r2 % OC);
  int n = (int)(r2 / OC);
  float s = bias[oc];
  const float* xb = x + ((size_t)n * CI * HI) * WI;
  const float* wb = w + (size_t)oc * CI * 9;
  for (int c = 0; c < CI; ++c)
    for (int kh = 0; kh < 3; ++kh)
      for (int kw = 0; kw < 3; ++kw)
        s += xb[((size_t)c * HI + oh + kh) * WI + ow + kw] * wb[(c * 3 + kh) * 3 + kw];
  out[i] = s;
}

extern "C" void kernel_launch(void* const* d_in, const int* in_sizes, int n_in,
                              void* d_out, int out_size, void* d_ws, size_t ws_size,
                              hipStream_t stream) {
  const float* x = (const float*)d_in[0];
  const float* w = (const float*)d_in[1];
  const float* bias = (const float*)d_in[2];
  float* out = (float*)d_out;

  const size_t xn_elems = (size_t)NI * 4 * HI * WI * 32;  // 51,380,224
  const size_t wp_elems = (size_t)9 * 4 * 256 * 32;       // 294,912
  const size_t need = (xn_elems + wp_elems) * sizeof(ushort);

  if (ws_size >= need) {
    ushort* xnw = (ushort*)d_ws;
    ushort* wpw = xnw + xn_elems;
    hipLaunchKernelGGL(pack_w_kernel, dim3((unsigned)(wp_elems / 256)), dim3(256), 0, stream,
                       w, wpw);
    hipLaunchKernelGGL(to_nhwc_kernel, dim3(NI * HI), dim3(256), 0, stream, x, xnw);
    hipLaunchKernelGGL(conv_mfma_kernel, dim3(NI * HO), dim3(256), 0, stream, xnw, wpw, bias,
                       out);
  } else {
    long total = (long)NI * OC * HO * WO;
    hipLaunchKernelGGL(conv_naive_kernel, dim3((unsigned)((total + 255) / 256)), dim3(256), 0,
                       stream, x, w, bias, out);
  }
}

// Round 8
// 298.904 us; speedup vs baseline: 1.2136x; 1.0821x over previous
//
#include <hip/hip_runtime.h>

#define NI 32
#define CI 128
#define HI 112
#define WI 112
#define OC 256
#define HO 110
#define WO 110

typedef float f32x4 __attribute__((ext_vector_type(4)));
typedef short s16x8 __attribute__((ext_vector_type(8)));

typedef const unsigned int __attribute__((address_space(1))) gu32;
typedef unsigned int __attribute__((address_space(3))) lu32;

__device__ __forceinline__ ushort f2bf(float f) {
  union { float f; unsigned int u; } x; x.f = f;
  unsigned int r = x.u + 0x7FFFu + ((x.u >> 16) & 1u);
  return (ushort)(r >> 16);
}

// weight [oc][c][kh][kw] fp32 -> wp [kk][cq][oc][32ch] bf16  (cq = 32-ch quarter)
__global__ __launch_bounds__(256) void pack_w_kernel(const float* __restrict__ w,
                                                     ushort* __restrict__ wp) {
  int i = blockIdx.x * 256 + threadIdx.x;  // 294912
  int e = i & 7;
  int k8 = (i >> 3) & 3;
  int oc = (i >> 5) & 255;
  int cq = (i >> 13) & 3;
  int kk = i >> 15;  // 0..8
  int ch = cq * 32 + k8 * 8 + e;
  int kh = kk / 3, kw = kk - kh * 3;
  wp[i] = f2bf(w[((oc * CI + ch) * 3 + kh) * 3 + kw]);
}

// x [n][c][h][w] fp32 -> xn [n][cq][h][w][32c] bf16.
// Coalesced reads (lane<->w), 16B-chunk XOR-swizzled LDS transpose, uint4 writes.
__global__ __launch_bounds__(256) void to_nhwc_kernel(const float* __restrict__ x,
                                                      ushort* __restrict__ xn) {
  __shared__ ushort lds[1792 * 8];  // 1792 16B chunks (112 w x 16 chunks), 28 KB
  int b = blockIdx.x;               // n*112 + h
  int n = b / HI;
  int h = b - n * HI;
  const float* xr = x + ((size_t)n * CI * HI) * WI + (size_t)h * WI;
  int t = threadIdx.x;
  int w = t & 127;   // active if < 112
  int cph = t >> 7;  // 0..1
  if (w < WI) {
    #pragma unroll
    for (int it = 0; it < 32; ++it) {
      int cp = it * 2 + cph;  // channel pair 0..63
      int c = cp * 2;
      float f0 = xr[(size_t)c * (HI * WI) + w];
      float f1 = xr[(size_t)(c + 1) * (HI * WI) + w];
      unsigned int pk = (unsigned int)f2bf(f0) | ((unsigned int)f2bf(f1) << 16);
      int chunk = w * 16 + ((cp >> 2) ^ (w & 15));
      *(unsigned int*)((char*)lds + chunk * 16 + (cp & 3) * 4) = pk;
    }
  }
  __syncthreads();
  #pragma unroll
  for (int it = 0; it < 7; ++it) {
    int j = it * 256 + t;  // chunk id: w = j>>4, c8 = j&15
    int w2 = j >> 4, c8 = j & 15;
    int src = w2 * 16 + (c8 ^ (w2 & 15));
    uint4 v = *(const uint4*)((const char*)lds + src * 16);
    int cq = c8 >> 2, g = c8 & 3;
    *(uint4*)&xn[((((size_t)n * 4 + cq) * HI + h) * WI + w2) * 32 + g * 8] = v;
  }
}

// Implicit GEMM, 16x16x32 MFMA. Block = 256 thr (4 waves = 4 oc quarters),
// one output row x 256 oc. K = 4 quarters of 32 ch.
// TRIPLE-buffered LDS: stage(q+2) issued at the START of quarter q (~18 steps
// of slack; quarter-boundary __syncthreads drains only retired loads).
// Distance-2 A-prefetch: A(g+2) issued AFTER step g's MFMA cluster into the
// same-parity abuf (WAR pins order; no extra registers).
__global__ __launch_bounds__(256, 2) void conv_mfma_kernel(const ushort* __restrict__ xn,
                                                           const ushort* __restrict__ wp,
                                                           const float* __restrict__ bias,
                                                           float* __restrict__ out) {
  __shared__ ushort lds[3 * 340 * 32];  // 3 quarter buffers, 21.75 KB each = 65280 B
  const int bid = blockIdx.x;
  // bijective XCD swizzle (3520 = 8*440): consecutive oh share an XCD's L2
  const int orig = (bid & 7) * 440 + (bid >> 3);
  const int n = orig / HO;
  const int oh = orig - n * HO;
  const int t = threadIdx.x;
  const int lane = t & 63;
  const int wid = t >> 6;  // oc quarter
  const int lane15 = lane & 15;
  const int laneh = lane >> 4;  // 0..3
  const int oc0 = wid * 64;
  char* ldsb = (char*)lds;

  f32x4 acc[4][7] = {};  // [mf: oc 16-frag][nf: ow 16-frag]
  s16x8 abuf[2][4];      // A double-buffer (static indices after unroll)

#define A_PREFETCH(gg)                                                                   \
  {                                                                                      \
    const int q_ = (gg) / 9, kk_ = (gg) - q_ * 9;                                        \
    const ushort* wb_ = wp + ((size_t)(kk_ * 4 + q_)) * 8192 + (oc0 + lane15) * 32 +     \
                        laneh * 8;                                                       \
    _Pragma("unroll") for (int mf = 0; mf < 4; ++mf)                                     \
        abuf[(gg) & 1][mf] = *(const s16x8*)(wb_ + mf * 512);                            \
  }

#define STAGE(qq)                                                                        \
  {                                                                                      \
    const char* gsb_ =                                                                   \
        (const char*)(xn + ((((size_t)n * 4 + (qq)) * HI + oh) * WI) * 32);              \
    char* ldst_ = ldsb + (((qq) % 3) * 21760);                                           \
    _Pragma("unroll") for (int i = 0; i < 6; ++i) {                                      \
      int idx = i * 256 + t;                                                             \
      if (idx < 1344) {                                                                  \
        int L = idx * 16;                                                                \
        int go = L ^ (((L >> 7) & 3) << 4);                                              \
        __builtin_amdgcn_global_load_lds((gu32*)(gsb_ + go), (lu32*)(ldst_ + L), 16, 0,  \
                                         0);                                             \
      }                                                                                  \
    }                                                                                    \
  }

  // ---- prologue: A(0), A(1) first (clean waits), then stage(0), stage(1) ----
  A_PREFETCH(0)
  A_PREFETCH(1)
  STAGE(0)
  STAGE(1)
  __syncthreads();  // drains prologue (once per block)

  #pragma unroll
  for (int q = 0; q < 4; ++q) {
    if (q) __syncthreads();  // all in-flight loads here are ~9 steps old: free drain
    if (q < 2) STAGE(q + 2)  // triple-buffer: 2-quarter lead time
    const int qb = (q % 3) * 21760;
    #pragma unroll
    for (int kk = 0; kk < 9; ++kk) {
      const int g = q * 9 + kk;
      const int kh = kk / 3, kw = kk - kh * 3;
      // B fragments from swizzled LDS quarter
      s16x8 b[7];
      #pragma unroll
      for (int nf = 0; nf < 7; ++nf) {
        int R = kh * WI + nf * 16 + lane15 + kw;  // staged pixel-row index
        int addr = qb + (R << 6) + ((laneh ^ ((R >> 1) & 3)) << 4);
        b[nf] = *(const s16x8*)(ldsb + addr);
      }
      __builtin_amdgcn_s_setprio(1);
      #pragma unroll
      for (int mf = 0; mf < 4; ++mf)
        #pragma unroll
        for (int nf = 0; nf < 7; ++nf)
          acc[mf][nf] = __builtin_amdgcn_mfma_f32_16x16x32_bf16(abuf[g & 1][mf], b[nf],
                                                                acc[mf][nf], 0, 0, 0);
      __builtin_amdgcn_s_setprio(0);
      // distance-2 A-prefetch into the regs just consumed (WAR pins order)
      if (g + 2 < 36) A_PREFETCH(g + 2)
    }
  }
#undef A_PREFETCH
#undef STAGE

  // ---- epilogue: D col=lane15 -> ow, row=laneh*4+r -> oc ----
  float* outb = out + ((size_t)n * OC) * (HO * WO) + (size_t)oh * WO;
  #pragma unroll
  for (int mf = 0; mf < 4; ++mf) {
    #pragma unroll
    for (int r = 0; r < 4; ++r) {
      const int oc = oc0 + mf * 16 + laneh * 4 + r;
      const float bv = bias[oc];
      float* op = outb + (size_t)oc * (HO * WO);
      #pragma unroll
      for (int nf = 0; nf < 7; ++nf) {
        int ow = nf * 16 + lane15;
        if (ow < WO) op[ow] = acc[mf][nf][r] + bv;
      }
    }
  }
}

// Correctness fallback if ws is too small for the packed bf16 buffers.
__global__ __launch_bounds__(256) void conv_naive_kernel(const float* __restrict__ x,
                                                         const float* __restrict__ w,
                                                         const float* __restrict__ bias,
                                                         float* __restrict__ out) {
  long i = (long)blockIdx.x * 256 + threadIdx.x;
  const long total = (long)NI * OC * HO * WO;
  if (i >= total) return;
  int ow = (int)(i % WO);
  long r1 = i / WO;
  int oh = (int)(r1 % HO);
  long r2 = r1 / HO;
  int oc = (int)(r2 % OC);
  int n = (int)(r2 / OC);
  float s = bias[oc];
  const float* xb = x + ((size_t)n * CI * HI) * WI;
  const float* wb = w + (size_t)oc * CI * 9;
  for (int c = 0; c < CI; ++c)
    for (int kh = 0; kh < 3; ++kh)
      for (int kw = 0; kw < 3; ++kw)
        s += xb[((size_t)c * HI + oh + kh) * WI + ow + kw] * wb[(c * 3 + kh) * 3 + kw];
  out[i] = s;
}

extern "C" void kernel_launch(void* const* d_in, const int* in_sizes, int n_in,
                              void* d_out, int out_size, void* d_ws, size_t ws_size,
                              hipStream_t stream) {
  const float* x = (const float*)d_in[0];
  const float* w = (const float*)d_in[1];
  const float* bias = (const float*)d_in[2];
  float* out = (float*)d_out;

  const size_t xn_elems = (size_t)NI * 4 * HI * WI * 32;  // 51,380,224
  const size_t wp_elems = (size_t)9 * 4 * 256 * 32;       // 294,912
  const size_t need = (xn_elems + wp_elems) * sizeof(ushort);

  if (ws_size >= need) {
    ushort* xnw = (ushort*)d_ws;
    ushort* wpw = xnw + xn_elems;
    hipLaunchKernelGGL(pack_w_kernel, dim3((unsigned)(wp_elems / 256)), dim3(256), 0, stream,
                       w, wpw);
    hipLaunchKernelGGL(to_nhwc_kernel, dim3(NI * HI), dim3(256), 0, stream, x, xnw);
    hipLaunchKernelGGL(conv_mfma_kernel, dim3(NI * HO), dim3(256), 0, stream, xnw, wpw, bias,
                       out);
  } else {
    long total = (long)NI * OC * HO * WO;
    hipLaunchKernelGGL(conv_naive_kernel, dim3((unsigned)((total + 255) / 256)), dim3(256), 0,
                       stream, x, w, bias, out);
  }
}